// Round 1
// baseline (200.901 us; speedup 1.0000x reference)
//
#include <hip/hip_runtime.h>
#include <math.h>

// Problem constants (fixed by the reference setup)
#define BB 2
#define MM 2048   // x positions (attention "keys", softmax axis)
#define NN 2048   // y positions (attention "queries")
#define EE 128
#define KH 8
#define DD 16
#define MSPLIT 4
#define MCHUNK (MM / MSPLIT)

// ---------------------------------------------------------------------------
// Kernel 1: projections.
//  f=0: rK  = x @ lambda1 + bias_lambda   [B][K][M][D]   (attention K)
//  f=1: xtV = x @ theta1                  [B][K][M][D]   (attention V)
//  f=2: kyQ = y @ lambda2                 [B][K][N][D]   (attention Q)
// ---------------------------------------------------------------------------
__global__ __launch_bounds__(256) void proj_kernel(
    const float* __restrict__ x, const float* __restrict__ y,
    const float* __restrict__ lambda1, const float* __restrict__ lambda2,
    const float* __restrict__ theta1, const float* __restrict__ bias_lambda,
    float* __restrict__ rK, float* __restrict__ kyQ, float* __restrict__ xtV)
{
    __shared__ float xs[16][132];   // +4 pad: rows land on distinct banks
    __shared__ float Ws[128][16];

    const int tile = blockIdx.x;          // B*K*(M/16) = 2048
    const int mt = tile & 127;            // m-tile
    const int k  = (tile >> 7) & 7;
    const int b  = tile >> 10;
    const int f  = blockIdx.y;
    const int tid = threadIdx.x;

    const float* src = (f == 2) ? y : x;
    const float* W   = (f == 0) ? lambda1 : ((f == 1) ? theta1 : lambda2);
    float* dst       = (f == 0) ? rK      : ((f == 1) ? xtV    : kyQ);

    // stage src tile [16][128]
    const float* sp = src + ((size_t)b * MM + (size_t)mt * 16) * EE;
    for (int i = tid; i < 512; i += 256) {
        float4 v = ((const float4*)sp)[i];
        int row = i >> 5, cp = (i & 31) * 4;
        *(float4*)&xs[row][cp] = v;
    }
    // stage weights [128][16]
    const float* wp = W + (size_t)k * (EE * DD);
    for (int i = tid; i < 512; i += 256) {
        float4 v = ((const float4*)wp)[i];
        int row = i >> 2, cp = (i & 3) * 4;
        *(float4*)&Ws[row][cp] = v;
    }
    __syncthreads();

    const int row = tid >> 4, col = tid & 15;
    float acc = (f == 0) ? bias_lambda[k * DD + col] : 0.0f;
    #pragma unroll 16
    for (int p = 0; p < EE; ++p)
        acc = fmaf(xs[row][p], Ws[p][col], acc);

    dst[(((size_t)b * KH + k) * MM + (size_t)mt * 16 + row) * DD + col] = acc;
}

// ---------------------------------------------------------------------------
// Kernel 2: flash attention over m, split MSPLIT ways (flash-decoding style).
// Thread-per-query: each thread owns one n, holds Q[16] and O[16] in regs.
// Writes unnormalized partial O + (running max, running sum) per split.
// ---------------------------------------------------------------------------
__global__ __launch_bounds__(256) void attn_kernel(
    const float* __restrict__ rK, const float* __restrict__ kyQ,
    const float* __restrict__ xtV,
    float* __restrict__ Opart, float* __restrict__ mlP)
{
    __shared__ float Ks[32][16];
    __shared__ float Vs[32][16];

    const int nt   = blockIdx.x & 7;      // n-tile (N/256 = 8)
    const int head = blockIdx.x >> 3;     // b*KH + k, 0..15
    const int ms   = blockIdx.y;          // m-split index
    const int tid  = threadIdx.x;
    const int n    = nt * 256 + tid;

    // Q into registers
    float q[16];
    {
        const float4* qp = (const float4*)(kyQ + ((size_t)head * NN + n) * DD);
        float4 q0 = qp[0], q1 = qp[1], q2 = qp[2], q3 = qp[3];
        q[0]=q0.x; q[1]=q0.y; q[2]=q0.z; q[3]=q0.w;
        q[4]=q1.x; q[5]=q1.y; q[6]=q1.z; q[7]=q1.w;
        q[8]=q2.x; q[9]=q2.y; q[10]=q2.z; q[11]=q2.w;
        q[12]=q3.x; q[13]=q3.y; q[14]=q3.z; q[15]=q3.w;
    }

    float o[16];
    #pragma unroll
    for (int i = 0; i < 16; ++i) o[i] = 0.f;
    float mmax = -INFINITY, l = 0.f;

    const int m0base = ms * MCHUNK;
    const float* kbase = rK  + ((size_t)head * MM) * DD;
    const float* vbase = xtV + ((size_t)head * MM) * DD;

    for (int it = 0; it < MCHUNK / 32; ++it) {
        const int m0 = m0base + it * 32;
        __syncthreads();
        // stage K,V tile: 32 rows x 16 f32 each = 128 float4 apiece
        if (tid < 128) {
            ((float4*)Ks)[tid] = ((const float4*)(kbase + (size_t)m0 * DD))[tid];
        } else if (tid < 256) {
            ((float4*)Vs)[tid - 128] = ((const float4*)(vbase + (size_t)m0 * DD))[tid - 128];
        }
        __syncthreads();

        float s[32];
        float tm = -INFINITY;
        #pragma unroll
        for (int mm2 = 0; mm2 < 32; ++mm2) {
            const float4* kr = (const float4*)&Ks[mm2][0];
            float4 ka = kr[0], kb = kr[1], kc = kr[2], kd = kr[3];
            float acc;
            acc = q[0]*ka.x;
            acc = fmaf(q[1], ka.y, acc); acc = fmaf(q[2], ka.z, acc); acc = fmaf(q[3], ka.w, acc);
            acc = fmaf(q[4], kb.x, acc); acc = fmaf(q[5], kb.y, acc); acc = fmaf(q[6], kb.z, acc); acc = fmaf(q[7], kb.w, acc);
            acc = fmaf(q[8], kc.x, acc); acc = fmaf(q[9], kc.y, acc); acc = fmaf(q[10], kc.z, acc); acc = fmaf(q[11], kc.w, acc);
            acc = fmaf(q[12], kd.x, acc); acc = fmaf(q[13], kd.y, acc); acc = fmaf(q[14], kd.z, acc); acc = fmaf(q[15], kd.w, acc);
            s[mm2] = acc * 0.25f;      // head_dim^-0.5 = 16^-0.5
            tm = fmaxf(tm, s[mm2]);
        }
        const float newm = fmaxf(mmax, tm);
        const float c = __expf(mmax - newm);   // first tile: exp(-inf)=0
        l *= c;
        #pragma unroll
        for (int dd2 = 0; dd2 < 16; ++dd2) o[dd2] *= c;
        #pragma unroll
        for (int mm2 = 0; mm2 < 32; ++mm2) {
            const float p = __expf(s[mm2] - newm);
            l += p;
            const float4* vr = (const float4*)&Vs[mm2][0];
            float4 va = vr[0], vb = vr[1], vc = vr[2], vd = vr[3];
            o[0]  = fmaf(p, va.x, o[0]);  o[1]  = fmaf(p, va.y, o[1]);
            o[2]  = fmaf(p, va.z, o[2]);  o[3]  = fmaf(p, va.w, o[3]);
            o[4]  = fmaf(p, vb.x, o[4]);  o[5]  = fmaf(p, vb.y, o[5]);
            o[6]  = fmaf(p, vb.z, o[6]);  o[7]  = fmaf(p, vb.w, o[7]);
            o[8]  = fmaf(p, vc.x, o[8]);  o[9]  = fmaf(p, vc.y, o[9]);
            o[10] = fmaf(p, vc.z, o[10]); o[11] = fmaf(p, vc.w, o[11]);
            o[12] = fmaf(p, vd.x, o[12]); o[13] = fmaf(p, vd.y, o[13]);
            o[14] = fmaf(p, vd.z, o[14]); o[15] = fmaf(p, vd.w, o[15]);
        }
        mmax = newm;
    }

    float4* op = (float4*)(Opart + (((size_t)ms * (BB * KH) + head) * NN + n) * DD);
    op[0] = make_float4(o[0],  o[1],  o[2],  o[3]);
    op[1] = make_float4(o[4],  o[5],  o[6],  o[7]);
    op[2] = make_float4(o[8],  o[9],  o[10], o[11]);
    op[3] = make_float4(o[12], o[13], o[14], o[15]);
    const size_t mlbase = (((size_t)ms * (BB * KH) + head) * NN + n) * 2;
    mlP[mlbase]     = mmax;
    mlP[mlbase + 1] = l;
}

// ---------------------------------------------------------------------------
// Kernel 3: merge m-splits -> r2 (+bias_theta), then out = r2 @ theta2^T.
// One block per 2 query rows (all 8 heads).
// ---------------------------------------------------------------------------
__global__ __launch_bounds__(256) void combine_kernel(
    const float* __restrict__ Opart, const float* __restrict__ mlP,
    const float* __restrict__ bias_theta, const float* __restrict__ theta2,
    float* __restrict__ out)
{
    __shared__ float r2s[2][128];   // [n_loc][k*16+d]

    const int pairIdx = blockIdx.x;       // B*N/2 = 2048
    const int b   = pairIdx >> 10;
    const int np0 = (pairIdx & 1023) * 2;
    const int tid = threadIdx.x;

    {
        const int n_loc = tid >> 7;
        const int rem = tid & 127;
        const int k = rem >> 4, dd = rem & 15;
        const int n = np0 + n_loc;
        const int head = b * KH + k;

        float mm[MSPLIT], ls[MSPLIT];
        float Mx = -INFINITY;
        #pragma unroll
        for (int s2 = 0; s2 < MSPLIT; ++s2) {
            const size_t base = ((size_t)s2 * (BB * KH) + head) * NN + n;
            mm[s2] = mlP[base * 2];
            ls[s2] = mlP[base * 2 + 1];
            Mx = fmaxf(Mx, mm[s2]);
        }
        float L = 0.f, O = 0.f;
        #pragma unroll
        for (int s2 = 0; s2 < MSPLIT; ++s2) {
            const float w = __expf(mm[s2] - Mx);
            L += ls[s2] * w;
            O = fmaf(Opart[(((size_t)s2 * (BB * KH) + head) * NN + n) * DD + dd], w, O);
        }
        r2s[n_loc][rem] = O / L + bias_theta[k * DD + dd];
    }
    __syncthreads();
    {
        const int n_loc = tid >> 7;
        const int qq = tid & 127;
        const int n = np0 + n_loc;
        float acc = 0.f;
        #pragma unroll
        for (int k = 0; k < KH; ++k) {
            const float4* t2 = (const float4*)(theta2 + ((size_t)k * EE + qq) * DD);
            const float* r2p = &r2s[n_loc][k * DD];
            float4 t0 = t2[0], t1 = t2[1], t2v = t2[2], t3 = t2[3];
            acc = fmaf(r2p[0],  t0.x, acc); acc = fmaf(r2p[1],  t0.y, acc);
            acc = fmaf(r2p[2],  t0.z, acc); acc = fmaf(r2p[3],  t0.w, acc);
            acc = fmaf(r2p[4],  t1.x, acc); acc = fmaf(r2p[5],  t1.y, acc);
            acc = fmaf(r2p[6],  t1.z, acc); acc = fmaf(r2p[7],  t1.w, acc);
            acc = fmaf(r2p[8],  t2v.x, acc); acc = fmaf(r2p[9],  t2v.y, acc);
            acc = fmaf(r2p[10], t2v.z, acc); acc = fmaf(r2p[11], t2v.w, acc);
            acc = fmaf(r2p[12], t3.x, acc); acc = fmaf(r2p[13], t3.y, acc);
            acc = fmaf(r2p[14], t3.z, acc); acc = fmaf(r2p[15], t3.w, acc);
        }
        out[((size_t)b * NN + n) * EE + qq] = acc;
    }
}

// ---------------------------------------------------------------------------
extern "C" void kernel_launch(void* const* d_in, const int* in_sizes, int n_in,
                              void* d_out, int out_size, void* d_ws, size_t ws_size,
                              hipStream_t stream) {
    const float* x           = (const float*)d_in[0];
    const float* y           = (const float*)d_in[1];
    const float* lambda1     = (const float*)d_in[2];
    const float* lambda2     = (const float*)d_in[3];
    const float* theta1      = (const float*)d_in[4];
    const float* theta2      = (const float*)d_in[5];
    const float* bias_lambda = (const float*)d_in[6];
    const float* bias_theta  = (const float*)d_in[7];
    float* out = (float*)d_out;
    float* ws  = (float*)d_ws;

    // Workspace layout (floats):
    //   rK    [B][K][M][D]          524288
    //   kyQ   [B][K][N][D]          524288
    //   xtV   [B][K][M][D]          524288
    //   Opart [MSPLIT][B*K][N][D]   4*524288
    //   mlP   [MSPLIT][B*K][N][2]   262144
    // total ~15.7 MB
    const size_t HSZ = (size_t)BB * KH * MM * DD;
    float* rK    = ws;
    float* kyQ   = rK + HSZ;
    float* xtV   = kyQ + HSZ;
    float* Opart = xtV + HSZ;
    float* mlP   = Opart + (size_t)MSPLIT * HSZ;

    hipLaunchKernelGGL(proj_kernel, dim3(2048, 3), dim3(256), 0, stream,
                       x, y, lambda1, lambda2, theta1, bias_lambda, rK, kyQ, xtV);
    hipLaunchKernelGGL(attn_kernel, dim3(128, MSPLIT), dim3(256), 0, stream,
                       rK, kyQ, xtV, Opart, mlP);
    hipLaunchKernelGGL(combine_kernel, dim3(2048), dim3(256), 0, stream,
                       Opart, mlP, bias_theta, theta2, out);
}

// Round 3
// 130.943 us; speedup vs baseline: 1.5343x; 1.5343x over previous
//
#include <hip/hip_runtime.h>
#include <math.h>

// Problem constants (fixed by the reference setup)
#define BB 2
#define MM 2048   // x positions (attention "keys", softmax axis)
#define NN 2048   // y positions (attention "queries")
#define EE 128
#define KH 8
#define DD 16
#define NHEADS (BB * KH)
#define MSPLIT 4
#define MCHUNK (MM / MSPLIT)

typedef __bf16 bf16x8 __attribute__((ext_vector_type(8)));
typedef __bf16 bf16x4 __attribute__((ext_vector_type(4)));
typedef float  f32x16 __attribute__((ext_vector_type(16)));
typedef float  f32x4  __attribute__((ext_vector_type(4)));

// ---------------------------------------------------------------------------
// Kernel 1: projections -> bf16.
//  f=0: rK  = x @ lambda1 + bias_lambda       [head][m][16]   (attention K)
//  f=1: Vt  = (x @ theta1)^T                  [head][16][m]   (attention V, transposed)
//  f=2: kyQ = 0.25 * (y @ lambda2)            [head][n][16]   (attention Q, pre-scaled)
// ---------------------------------------------------------------------------
__global__ __launch_bounds__(256) void proj_kernel(
    const float* __restrict__ x, const float* __restrict__ y,
    const float* __restrict__ lambda1, const float* __restrict__ lambda2,
    const float* __restrict__ theta1, const float* __restrict__ bias_lambda,
    __bf16* __restrict__ rK, __bf16* __restrict__ kyQ, __bf16* __restrict__ Vt)
{
    __shared__ float xs[16][132];   // +4 pad
    __shared__ float Ws[128][16];
    __shared__ float ts[16][17];    // transpose staging for f==1

    const int tile = blockIdx.x;          // B*K*(M/16) = 2048
    const int mt = tile & 127;            // m-tile
    const int k  = (tile >> 7) & 7;
    const int b  = tile >> 10;
    const int f  = blockIdx.y;
    const int tid = threadIdx.x;
    const int head = b * KH + k;

    const float* src = (f == 2) ? y : x;
    const float* W   = (f == 0) ? lambda1 : ((f == 1) ? theta1 : lambda2);

    // stage src tile [16][128]
    const float* sp = src + ((size_t)b * MM + (size_t)mt * 16) * EE;
    for (int i = tid; i < 512; i += 256) {
        float4 v = ((const float4*)sp)[i];
        int row = i >> 5, cp = (i & 31) * 4;
        *(float4*)&xs[row][cp] = v;
    }
    // stage weights [128][16]
    const float* wp = W + (size_t)k * (EE * DD);
    for (int i = tid; i < 512; i += 256) {
        float4 v = ((const float4*)wp)[i];
        int row = i >> 2, cp = (i & 3) * 4;
        *(float4*)&Ws[row][cp] = v;
    }
    __syncthreads();

    const int row = tid >> 4, col = tid & 15;
    float acc = (f == 0) ? bias_lambda[k * DD + col] : 0.0f;
    #pragma unroll 16
    for (int p = 0; p < EE; ++p)
        acc = fmaf(xs[row][p], Ws[p][col], acc);

    const int m = mt * 16 + row;
    if (f == 0) {
        rK[((size_t)head * MM + m) * DD + col] = (__bf16)acc;
    } else if (f == 2) {
        kyQ[((size_t)head * NN + m) * DD + col] = (__bf16)(acc * 0.25f);
    } else {
        ts[col][row] = acc;          // ts[d][m_loc]
        __syncthreads();
        const int dd2 = tid >> 4, mloc = tid & 15;
        Vt[((size_t)head * DD + dd2) * MM + mt * 16 + mloc] = (__bf16)ts[dd2][mloc];
    }
}

// ---------------------------------------------------------------------------
// Kernel 2: MFMA flash attention over m (split MSPLIT ways).
// Block = 4 waves; each wave owns 32 queries (n). Per 32-m chunk:
//   S^T = mfma_32x32x16(K_frag, Q_frag)  -> lane owns column n=lane&31
//   online softmax lane-local (+1 shfl_xor pair combine)
//   P -> wave-private LDS -> A-frags -> 2x mfma_16x16x32 PV (n halves)
// No __syncthreads anywhere in the loop.
// ---------------------------------------------------------------------------
__global__ __launch_bounds__(256) void attn_kernel(
    const __bf16* __restrict__ rK, const __bf16* __restrict__ kyQ,
    const __bf16* __restrict__ Vt,
    float* __restrict__ Opart, float* __restrict__ mlP)
{
    __shared__ __bf16 Pst[4][32][40];   // [wave][n][m] pad->40 (16B-aligned rows)

    const int tid  = threadIdx.x;
    const int wave = tid >> 6;
    const int lane = tid & 63;
    const int head = blockIdx.x >> 4;             // 0..15 = b*KH+k
    const int nbase = (blockIdx.x & 15) * 128 + wave * 32;
    const int ms   = blockIdx.y;

    const int l31 = lane & 31;
    const int hi  = lane >> 5;     // 0/1
    const int l15 = lane & 15;
    const int g4  = lane >> 4;     // 0..3

    // Q fragment: Q[nbase+l31][8*hi + e]  (B-operand of 32x32x16)
    const bf16x8 qf = *reinterpret_cast<const bf16x8*>(
        kyQ + ((size_t)head * NN + nbase + l31) * DD + 8 * hi);

    f32x4 o0, o1;
    #pragma unroll
    for (int i = 0; i < 4; ++i) { o0[i] = 0.f; o1[i] = 0.f; }
    float mmax = -INFINITY, lsum = 0.f;

    const __bf16* kb = rK + (size_t)head * MM * DD;
    const __bf16* vb = Vt + (size_t)head * DD * MM;

    for (int it = 0; it < MCHUNK / 32; ++it) {
        const int m0 = ms * MCHUNK + it * 32;

        // K fragment: K[m0+l31][8*hi + e]  (A-operand)
        const bf16x8 kf = *reinterpret_cast<const bf16x8*>(
            kb + ((size_t)(m0 + l31)) * DD + 8 * hi);

        f32x16 s;
        #pragma unroll
        for (int i = 0; i < 16; ++i) s[i] = 0.f;
        s = __builtin_amdgcn_mfma_f32_32x32x16_bf16(kf, qf, s, 0, 0, 0);
        // lane holds S[m'][n=l31], m' = (r&3) + 8*(r>>2) + 4*hi

        // online softmax (per n = l31; lanes l and l^32 are partners)
        float tm = s[0];
        #pragma unroll
        for (int r = 1; r < 16; ++r) tm = fmaxf(tm, s[r]);
        tm = fmaxf(tm, __shfl_xor(tm, 32));
        const float newm = fmaxf(mmax, tm);
        const float c = __expf(mmax - newm);   // first chunk: exp(-inf)=0

        float p[16];
        float ps = 0.f;
        #pragma unroll
        for (int r = 0; r < 16; ++r) { p[r] = __expf(s[r] - newm); ps += p[r]; }
        ps += __shfl_xor(ps, 32);
        lsum = lsum * c + ps;
        mmax = newm;

        // write P (bf16) to wave-private LDS: reg-quad qd covers m' = 8*qd+4*hi+j
        #pragma unroll
        for (int qd = 0; qd < 4; ++qd) {
            bf16x4 pk;
            pk[0] = (__bf16)p[4 * qd + 0];
            pk[1] = (__bf16)p[4 * qd + 1];
            pk[2] = (__bf16)p[4 * qd + 2];
            pk[3] = (__bf16)p[4 * qd + 3];
            *reinterpret_cast<bf16x4*>(&Pst[wave][l31][8 * qd + 4 * hi]) = pk;
        }

        // V fragment (B-operand of 16x16x32): V[m0 + 8*g4 + e][d=l15]
        const bf16x8 vf = *reinterpret_cast<const bf16x8*>(
            vb + (size_t)l15 * MM + m0 + 8 * g4);

        // P A-fragments: A[row=n_half_local=l15][k=m=8*g4+e]
        const bf16x8 pa0 = *reinterpret_cast<const bf16x8*>(&Pst[wave][l15][8 * g4]);
        const bf16x8 pa1 = *reinterpret_cast<const bf16x8*>(&Pst[wave][16 + l15][8 * g4]);

        // rescale O by c of each owned n, then accumulate PV
        #pragma unroll
        for (int r = 0; r < 4; ++r) {
            const float c0 = __shfl(c, 4 * g4 + r);
            const float c1 = __shfl(c, 16 + 4 * g4 + r);
            o0[r] *= c0;
            o1[r] *= c1;
        }
        o0 = __builtin_amdgcn_mfma_f32_16x16x32_bf16(pa0, vf, o0, 0, 0, 0);
        o1 = __builtin_amdgcn_mfma_f32_16x16x32_bf16(pa1, vf, o1, 0, 0, 0);
    }

    // epilogue: unnormalized O + (m, l) per n
    float* obase = Opart + ((size_t)ms * NHEADS + head) * NN * DD;
    #pragma unroll
    for (int r = 0; r < 4; ++r) {
        const int n0 = nbase + 4 * g4 + r;
        const int n1 = n0 + 16;
        obase[(size_t)n0 * DD + l15] = o0[r];
        obase[(size_t)n1 * DD + l15] = o1[r];
    }
    if (lane < 32) {
        const size_t mlbase = (((size_t)ms * NHEADS + head) * NN + nbase + l31) * 2;
        mlP[mlbase]     = mmax;
        mlP[mlbase + 1] = lsum;
    }
}

// ---------------------------------------------------------------------------
// Kernel 3: merge m-splits -> r2 (+bias_theta), then out = r2 @ theta2^T.
// ---------------------------------------------------------------------------
__global__ __launch_bounds__(256) void combine_kernel(
    const float* __restrict__ Opart, const float* __restrict__ mlP,
    const float* __restrict__ bias_theta, const float* __restrict__ theta2,
    float* __restrict__ out)
{
    __shared__ float r2s[2][128];   // [n_loc][k*16+d]

    const int pairIdx = blockIdx.x;       // B*N/2 = 2048
    const int b   = pairIdx >> 10;
    const int np0 = (pairIdx & 1023) * 2;
    const int tid = threadIdx.x;

    {
        const int n_loc = tid >> 7;
        const int rem = tid & 127;
        const int k = rem >> 4, dd = rem & 15;
        const int n = np0 + n_loc;
        const int head = b * KH + k;

        float mm[MSPLIT], ls[MSPLIT];
        float Mx = -INFINITY;
        #pragma unroll
        for (int s2 = 0; s2 < MSPLIT; ++s2) {
            const size_t base = ((size_t)s2 * NHEADS + head) * NN + n;
            mm[s2] = mlP[base * 2];
            ls[s2] = mlP[base * 2 + 1];
            Mx = fmaxf(Mx, mm[s2]);
        }
        float L = 0.f, O = 0.f;
        #pragma unroll
        for (int s2 = 0; s2 < MSPLIT; ++s2) {
            const float w = __expf(mm[s2] - Mx);
            L += ls[s2] * w;
            O = fmaf(Opart[(((size_t)s2 * NHEADS + head) * NN + n) * DD + dd], w, O);
        }
        r2s[n_loc][rem] = O / L + bias_theta[k * DD + dd];
    }
    __syncthreads();
    {
        const int n_loc = tid >> 7;
        const int qq = tid & 127;
        const int n = np0 + n_loc;
        float acc = 0.f;
        #pragma unroll
        for (int k = 0; k < KH; ++k) {
            const float4* t2 = (const float4*)(theta2 + ((size_t)k * EE + qq) * DD);
            const float* r2p = &r2s[n_loc][k * DD];
            float4 t0 = t2[0], t1 = t2[1], t2v = t2[2], t3 = t2[3];
            acc = fmaf(r2p[0],  t0.x, acc); acc = fmaf(r2p[1],  t0.y, acc);
            acc = fmaf(r2p[2],  t0.z, acc); acc = fmaf(r2p[3],  t0.w, acc);
            acc = fmaf(r2p[4],  t1.x, acc); acc = fmaf(r2p[5],  t1.y, acc);
            acc = fmaf(r2p[6],  t1.z, acc); acc = fmaf(r2p[7],  t1.w, acc);
            acc = fmaf(r2p[8],  t2v.x, acc); acc = fmaf(r2p[9],  t2v.y, acc);
            acc = fmaf(r2p[10], t2v.z, acc); acc = fmaf(r2p[11], t2v.w, acc);
            acc = fmaf(r2p[12], t3.x, acc); acc = fmaf(r2p[13], t3.y, acc);
            acc = fmaf(r2p[14], t3.z, acc); acc = fmaf(r2p[15], t3.w, acc);
        }
        out[((size_t)b * NN + n) * EE + qq] = acc;
    }
}

// ---------------------------------------------------------------------------
extern "C" void kernel_launch(void* const* d_in, const int* in_sizes, int n_in,
                              void* d_out, int out_size, void* d_ws, size_t ws_size,
                              hipStream_t stream) {
    const float* x           = (const float*)d_in[0];
    const float* y           = (const float*)d_in[1];
    const float* lambda1     = (const float*)d_in[2];
    const float* lambda2     = (const float*)d_in[3];
    const float* theta1      = (const float*)d_in[4];
    const float* theta2      = (const float*)d_in[5];
    const float* bias_lambda = (const float*)d_in[6];
    const float* bias_theta  = (const float*)d_in[7];
    float* out = (float*)d_out;

    // Workspace layout (bytes):
    //   rK    [16][2048][16] bf16   1 MiB
    //   kyQ   [16][2048][16] bf16   1 MiB
    //   Vt    [16][16][2048] bf16   1 MiB
    //   Opart [MSPLIT][16][2048][16] f32   8 MiB
    //   mlP   [MSPLIT][16][2048][2]  f32   1 MiB
    char* w = (char*)d_ws;
    __bf16* rK  = (__bf16*)w;  w += (size_t)NHEADS * MM * DD * 2;
    __bf16* kyQ = (__bf16*)w;  w += (size_t)NHEADS * NN * DD * 2;
    __bf16* Vt  = (__bf16*)w;  w += (size_t)NHEADS * DD * MM * 2;
    float* Opart = (float*)w;  w += (size_t)MSPLIT * NHEADS * NN * DD * 4;
    float* mlP   = (float*)w;

    hipLaunchKernelGGL(proj_kernel, dim3(2048, 3), dim3(256), 0, stream,
                       x, y, lambda1, lambda2, theta1, bias_lambda, rK, kyQ, Vt);
    hipLaunchKernelGGL(attn_kernel, dim3(256, MSPLIT), dim3(256), 0, stream,
                       rK, kyQ, Vt, Opart, mlP);
    hipLaunchKernelGGL(combine_kernel, dim3(2048), dim3(256), 0, stream,
                       Opart, mlP, bias_theta, theta2, out);
}

// Round 4
// 116.315 us; speedup vs baseline: 1.7272x; 1.1258x over previous
//
#include <hip/hip_runtime.h>
#include <math.h>

// Problem constants (fixed by the reference setup)
#define BB 2
#define MM 2048   // x positions (attention "keys", softmax axis)
#define NN 2048   // y positions (attention "queries")
#define EE 128
#define KH 8
#define DD 16
#define NHEADS (BB * KH)
#define MSPLIT 8
#define MCHUNK (MM / MSPLIT)
#define LOG2E 1.44269504088896340736f
#define QSCALE (0.25f * LOG2E)      // head_dim^-0.5 folded with log2(e): scores in log2 domain
#define DEFER_THR 8.0f              // T13: p <= 2^8, safe in bf16/f32

typedef __bf16 bf16x8 __attribute__((ext_vector_type(8)));
typedef __bf16 bf16x4 __attribute__((ext_vector_type(4)));
typedef float  f32x16 __attribute__((ext_vector_type(16)));
typedef float  f32x4  __attribute__((ext_vector_type(4)));

__device__ inline bf16x8 cvt8(float4 a, float4 b) {
    bf16x8 r;
    r[0] = (__bf16)a.x; r[1] = (__bf16)a.y; r[2] = (__bf16)a.z; r[3] = (__bf16)a.w;
    r[4] = (__bf16)b.x; r[5] = (__bf16)b.y; r[6] = (__bf16)b.z; r[7] = (__bf16)b.w;
    return r;
}

// ---------------------------------------------------------------------------
// Kernel 1: MFMA projections -> bf16. grid (8, 3, 16), block 256 (4 waves).
//  f=0: rK  = x @ lambda1 + bias_lambda          [head][m][16]
//  f=1: Vt  = (x @ theta1)^T                     [head][16][m]  (operand-swapped MFMA)
//  f=2: kyQ = QSCALE * (y @ lambda2)             [head][n][16]
// One wave per 16-row m-tile, K=128 as 4 chained mfma_16x16x32_bf16.
// W fragment load pattern is IDENTICAL for A- and B-operand roles, so the
// transpose for f=1 is free (swap mfma operands).
// ---------------------------------------------------------------------------
__global__ __launch_bounds__(256) void proj_kernel(
    const float* __restrict__ x, const float* __restrict__ y,
    const float* __restrict__ lambda1, const float* __restrict__ lambda2,
    const float* __restrict__ theta1, const float* __restrict__ bias_lambda,
    __bf16* __restrict__ rK, __bf16* __restrict__ kyQ, __bf16* __restrict__ Vt)
{
    const int grp  = blockIdx.x;    // 0..7  (16 m-tiles each)
    const int f    = blockIdx.y;    // 0..2
    const int head = blockIdx.z;    // 0..15
    const int b = head >> 3, kh = head & 7;
    const int wave = threadIdx.x >> 6;
    const int lane = threadIdx.x & 63;
    const int l15 = lane & 15, g4 = lane >> 4;

    const float* W   = ((f == 0) ? lambda1 : (f == 1) ? theta1 : lambda2)
                       + (size_t)kh * EE * DD;
    const float* src = ((f == 2) ? y : x) + (size_t)b * MM * EE;

    // W fragments, register-resident across all m-tiles:
    // wf[kb][e] = W[32*kb + 8*g4 + e][l15]
    bf16x8 wf[4];
    #pragma unroll
    for (int kb = 0; kb < 4; ++kb) {
        const float* wp = W + (size_t)(32 * kb + 8 * g4) * DD + l15;
        bf16x8 t;
        #pragma unroll
        for (int e = 0; e < 8; ++e) t[e] = (__bf16)wp[e * DD];
        wf[kb] = t;
    }
    const float bl = (f == 0) ? bias_lambda[kh * DD + l15] : 0.f;

    for (int i = 0; i < 4; ++i) {
        const int m0 = (grp * 16 + wave * 4 + i) * 16;
        const float* xp = src + (size_t)(m0 + l15) * EE + 8 * g4;

        f32x4 acc;
        #pragma unroll
        for (int r = 0; r < 4; ++r) acc[r] = 0.f;

        #pragma unroll
        for (int kb = 0; kb < 4; ++kb) {
            float4 a = *(const float4*)(xp + 32 * kb);
            float4 c = *(const float4*)(xp + 32 * kb + 4);
            bf16x8 xf = cvt8(a, c);
            if (f == 1) acc = __builtin_amdgcn_mfma_f32_16x16x32_bf16(wf[kb], xf, acc, 0, 0, 0);
            else        acc = __builtin_amdgcn_mfma_f32_16x16x32_bf16(xf, wf[kb], acc, 0, 0, 0);
        }

        if (f == 0) {
            // D: row = m_loc = 4*g4+r, col = d = l15
            #pragma unroll
            for (int r = 0; r < 4; ++r)
                rK[((size_t)head * MM + m0 + 4 * g4 + r) * DD + l15] = (__bf16)(acc[r] + bl);
        } else if (f == 2) {
            #pragma unroll
            for (int r = 0; r < 4; ++r)
                kyQ[((size_t)head * NN + m0 + 4 * g4 + r) * DD + l15] = (__bf16)(acc[r] * QSCALE);
        } else {
            // D: row = d = 4*g4+r, col = m_loc = l15 -> already transposed
            #pragma unroll
            for (int r = 0; r < 4; ++r)
                Vt[((size_t)head * DD + 4 * g4 + r) * MM + m0 + l15] = (__bf16)acc[r];
        }
    }
}

// ---------------------------------------------------------------------------
// Kernel 2: MFMA flash attention over m (MSPLIT-way split). grid (256, 8).
// Scores in log2 domain (QSCALE folded into Q). Defer-max (T13): skip the
// O-rescale while per-chunk max grows < DEFER_THR. No __syncthreads in loop.
// ---------------------------------------------------------------------------
__global__ __launch_bounds__(256) void attn_kernel(
    const __bf16* __restrict__ rK, const __bf16* __restrict__ kyQ,
    const __bf16* __restrict__ Vt,
    float* __restrict__ Opart, float* __restrict__ mlP)
{
    __shared__ __bf16 Pst[4][32][40];   // [wave][n][m] pad->40 (16B-aligned rows)

    const int tid  = threadIdx.x;
    const int wave = tid >> 6;
    const int lane = tid & 63;
    const int head = blockIdx.x >> 4;             // 0..15 = b*KH+kh
    const int nbase = (blockIdx.x & 15) * 128 + wave * 32;
    const int ms   = blockIdx.y;
    const int b = head >> 3, kh = head & 7;

    const int l31 = lane & 31;
    const int hi  = lane >> 5;
    const int l15 = lane & 15;
    const int g4  = lane >> 4;

    const bf16x8 qf = *reinterpret_cast<const bf16x8*>(
        kyQ + ((size_t)head * NN + nbase + l31) * DD + 8 * hi);

    f32x4 o0, o1;
    #pragma unroll
    for (int i = 0; i < 4; ++i) { o0[i] = 0.f; o1[i] = 0.f; }
    float mmax = -INFINITY, lsum = 0.f;

    const __bf16* kb = rK + (size_t)head * MM * DD;
    const __bf16* vb = Vt + (size_t)head * DD * MM;

    for (int it = 0; it < MCHUNK / 32; ++it) {
        const int m0 = ms * MCHUNK + it * 32;

        const bf16x8 kf = *reinterpret_cast<const bf16x8*>(
            kb + ((size_t)(m0 + l31)) * DD + 8 * hi);

        f32x16 s;
        #pragma unroll
        for (int i = 0; i < 16; ++i) s[i] = 0.f;
        s = __builtin_amdgcn_mfma_f32_32x32x16_bf16(kf, qf, s, 0, 0, 0);
        // lane holds S[m'][n=l31] (log2 domain), m' = (r&3) + 8*(r>>2) + 4*hi

        float tm = s[0];
        #pragma unroll
        for (int r = 1; r < 16; ++r) tm = fmaxf(tm, s[r]);
        tm = fmaxf(tm, __shfl_xor(tm, 32));

        // T13 defer-max: wave-uniform branch (first chunk always rescales)
        if (!__all(tm - mmax <= DEFER_THR)) {
            const float newm = fmaxf(mmax, tm);
            const float c = exp2f(mmax - newm);    // first chunk: exp2(-inf)=0
            lsum *= c;
            #pragma unroll
            for (int r = 0; r < 4; ++r) {
                o0[r] *= __shfl(c, 4 * g4 + r);
                o1[r] *= __shfl(c, 16 + 4 * g4 + r);
            }
            mmax = newm;
        }

        float p[16];
        float ps = 0.f;
        #pragma unroll
        for (int r = 0; r < 16; ++r) { p[r] = exp2f(s[r] - mmax); ps += p[r]; }
        ps += __shfl_xor(ps, 32);
        lsum += ps;

        #pragma unroll
        for (int qd = 0; qd < 4; ++qd) {
            bf16x4 pk;
            pk[0] = (__bf16)p[4 * qd + 0];
            pk[1] = (__bf16)p[4 * qd + 1];
            pk[2] = (__bf16)p[4 * qd + 2];
            pk[3] = (__bf16)p[4 * qd + 3];
            *reinterpret_cast<bf16x4*>(&Pst[wave][l31][8 * qd + 4 * hi]) = pk;
        }

        const bf16x8 vf = *reinterpret_cast<const bf16x8*>(
            vb + (size_t)l15 * MM + m0 + 8 * g4);

        const bf16x8 pa0 = *reinterpret_cast<const bf16x8*>(&Pst[wave][l15][8 * g4]);
        const bf16x8 pa1 = *reinterpret_cast<const bf16x8*>(&Pst[wave][16 + l15][8 * g4]);

        o0 = __builtin_amdgcn_mfma_f32_16x16x32_bf16(pa0, vf, o0, 0, 0, 0);
        o1 = __builtin_amdgcn_mfma_f32_16x16x32_bf16(pa1, vf, o1, 0, 0, 0);
    }

    // Opart layout [ms][b][n][kh*16+d] for coalesced combine reads
    float* obase = Opart + (((size_t)ms * BB + b) * NN) * (KH * DD) + kh * DD;
    #pragma unroll
    for (int r = 0; r < 4; ++r) {
        const int n0 = nbase + 4 * g4 + r;
        const int n1 = n0 + 16;
        obase[(size_t)n0 * (KH * DD) + l15] = o0[r];
        obase[(size_t)n1 * (KH * DD) + l15] = o1[r];
    }
    if (lane < 32) {
        // mlP layout [ms][b][n][kh][2]
        const size_t mlbase = (((size_t)ms * BB + b) * NN + nbase + l31) * (KH * 2) + kh * 2;
        mlP[mlbase]     = mmax;   // log2 domain
        mlP[mlbase + 1] = lsum;
    }
}

// ---------------------------------------------------------------------------
// Kernel 3: merge m-splits -> r2 (+bias_theta), then out = r2 @ theta2^T.
// grid 1024 (4 query rows per block), block 256. Fully float4.
// ---------------------------------------------------------------------------
__global__ __launch_bounds__(256) void combine_kernel(
    const float* __restrict__ Opart, const float* __restrict__ mlP,
    const float* __restrict__ bias_theta, const float* __restrict__ theta2,
    float* __restrict__ out)
{
    __shared__ float r2s[4][128];   // [n_loc][k*16+d]

    const int blk = blockIdx.x;          // B*N/4 = 1024
    const int b   = blk >> 9;
    const int n0  = (blk & 511) * 4;
    const int tid = threadIdx.x;

    if (tid < 128) {
        const int n_loc = tid >> 5;      // 0..3
        const int k  = (tid >> 2) & 7;
        const int dq = tid & 3;
        const int n = n0 + n_loc;

        float mm[MSPLIT], ls[MSPLIT];
        float Mx = -INFINITY;
        #pragma unroll
        for (int s = 0; s < MSPLIT; ++s) {
            const size_t base = (((size_t)s * BB + b) * NN + n) * (KH * 2) + k * 2;
            mm[s] = mlP[base];
            ls[s] = mlP[base + 1];
            Mx = fmaxf(Mx, mm[s]);
        }
        float L = 0.f;
        float4 O = make_float4(0.f, 0.f, 0.f, 0.f);
        #pragma unroll
        for (int s = 0; s < MSPLIT; ++s) {
            const float w = exp2f(mm[s] - Mx);
            L = fmaf(ls[s], w, L);
            const float4 op = *(const float4*)(
                Opart + (((size_t)s * BB + b) * NN + n) * (KH * DD) + k * DD + dq * 4);
            O.x = fmaf(w, op.x, O.x); O.y = fmaf(w, op.y, O.y);
            O.z = fmaf(w, op.z, O.z); O.w = fmaf(w, op.w, O.w);
        }
        const float inv = 1.f / L;
        const float* bt = bias_theta + k * DD + dq * 4;
        float4 res;
        res.x = fmaf(O.x, inv, bt[0]);
        res.y = fmaf(O.y, inv, bt[1]);
        res.z = fmaf(O.z, inv, bt[2]);
        res.w = fmaf(O.w, inv, bt[3]);
        *(float4*)&r2s[n_loc][k * DD + dq * 4] = res;
    }
    __syncthreads();
    {
        const int q   = tid & 127;
        const int nl0 = tid >> 7;        // 0/1; also handles nl0+2
        float acc0 = 0.f, acc1 = 0.f;
        #pragma unroll
        for (int k = 0; k < KH; ++k) {
            const float4* t2 = (const float4*)(theta2 + ((size_t)k * EE + q) * DD);
            const float4* ra = (const float4*)&r2s[nl0][k * DD];
            const float4* rb = (const float4*)&r2s[nl0 + 2][k * DD];
            #pragma unroll
            for (int j = 0; j < 4; ++j) {
                const float4 t = t2[j];
                const float4 a = ra[j];
                const float4 bq = rb[j];
                acc0 = fmaf(a.x, t.x, acc0);  acc0 = fmaf(a.y, t.y, acc0);
                acc0 = fmaf(a.z, t.z, acc0);  acc0 = fmaf(a.w, t.w, acc0);
                acc1 = fmaf(bq.x, t.x, acc1); acc1 = fmaf(bq.y, t.y, acc1);
                acc1 = fmaf(bq.z, t.z, acc1); acc1 = fmaf(bq.w, t.w, acc1);
            }
        }
        out[((size_t)b * NN + n0 + nl0) * EE + q]     = acc0;
        out[((size_t)b * NN + n0 + nl0 + 2) * EE + q] = acc1;
    }
}

// ---------------------------------------------------------------------------
extern "C" void kernel_launch(void* const* d_in, const int* in_sizes, int n_in,
                              void* d_out, int out_size, void* d_ws, size_t ws_size,
                              hipStream_t stream) {
    const float* x           = (const float*)d_in[0];
    const float* y           = (const float*)d_in[1];
    const float* lambda1     = (const float*)d_in[2];
    const float* lambda2     = (const float*)d_in[3];
    const float* theta1      = (const float*)d_in[4];
    const float* theta2      = (const float*)d_in[5];
    const float* bias_lambda = (const float*)d_in[6];
    const float* bias_theta  = (const float*)d_in[7];
    float* out = (float*)d_out;

    // Workspace layout:
    //   rK    [16][2048][16] bf16          1 MiB
    //   kyQ   [16][2048][16] bf16          1 MiB
    //   Vt    [16][16][2048] bf16          1 MiB
    //   Opart [8][2][2048][128] f32       16 MiB
    //   mlP   [8][2][2048][16] f32         2 MiB
    char* w = (char*)d_ws;
    __bf16* rK  = (__bf16*)w;  w += (size_t)NHEADS * MM * DD * 2;
    __bf16* kyQ = (__bf16*)w;  w += (size_t)NHEADS * NN * DD * 2;
    __bf16* Vt  = (__bf16*)w;  w += (size_t)NHEADS * DD * MM * 2;
    float* Opart = (float*)w;  w += (size_t)MSPLIT * BB * NN * KH * DD * 4;
    float* mlP   = (float*)w;

    hipLaunchKernelGGL(proj_kernel, dim3(8, 3, 16), dim3(256), 0, stream,
                       x, y, lambda1, lambda2, theta1, bias_lambda, rK, kyQ, Vt);
    hipLaunchKernelGGL(attn_kernel, dim3(256, MSPLIT), dim3(256), 0, stream,
                       rK, kyQ, Vt, Opart, mlP);
    hipLaunchKernelGGL(combine_kernel, dim3(1024), dim3(256), 0, stream,
                       Opart, mlP, bias_theta, theta2, out);
}